// Round 5
// baseline (284.519 us; speedup 1.0000x reference)
//
#include <hip/hip_runtime.h>
#include <hip/hip_bf16.h>

#define BATCH 32
#define SEQ 4096
#define DMODEL 256
#define NCLS 5

typedef short          s8v  __attribute__((ext_vector_type(8)));  // 8 bf16 frag
typedef unsigned short u4v  __attribute__((ext_vector_type(4)));
typedef float          f4v  __attribute__((ext_vector_type(4)));  // C/D frag

// RNE fp32->bf16 via compiler path (fuses to v_cvt_pk_bf16_f32, m240)
__device__ __forceinline__ unsigned short f2bs(float f) {
    __hip_bfloat16 h = __float2bfloat16(f);
    return *reinterpret_cast<unsigned short*>(&h);
}
// DPP row_shr within 16-lane rows, 0-fill (bound_ctrl)
__device__ __forceinline__ float dpp_shr2(float v) {
    return __int_as_float(__builtin_amdgcn_update_dpp(
        0, __float_as_int(v), 0x112, 0xF, 0xF, true));
}
__device__ __forceinline__ float dpp_shr4(float v) {
    return __int_as_float(__builtin_amdgcn_update_dpp(
        0, __float_as_int(v), 0x114, 0xF, 0xF, true));
}
__device__ __forceinline__ float dpp_shr8(float v) {
    return __int_as_float(__builtin_amdgcn_update_dpp(
        0, __float_as_int(v), 0x118, 0xF, 0xF, true));
}
// ds_swizzle BitMode: lane -> lane|14 (broadcast c=7 lane of each parity pair)
__device__ __forceinline__ float swz_or14(float v) {
    return __int_as_float(__builtin_amdgcn_ds_swizzle(
        __float_as_int(v), 0x01DF));
}

// R4 post-mortem: (512,2) cap=128 < live set ~150 -> 37MB scratch spill.
// HIP __launch_bounds__ 2nd arg = min BLOCKS/CU (verified twice:
// (512,4)->VGPR 64, (512,2)->128). 512-thread blocks quantize occupancy
// at {2,4} waves/SIMD; 4 needs <=128 regs (spills). 256-thread blocks
// unlock 3 waves/SIMD: (256,3) -> cap 512/3 = 170 >= live set ~150.
//
// Block = 256 thr (4 waves), grid 1024 = 256 d x 4 batch-quarters.
// Wave owns 2 batches x 8 chunks (col m16 -> b_loc=m16&1, c=m16>>1);
// 8 groups of 512 timesteps; ZERO main-loop barriers (all LDS traffic
// wave-private; in-order DS pipe). Only MA' fragments live in regs;
// CAT/TG/cq/hcp re-read from LDS per group. x loads go DIRECTLY
// global->B-frags (x is L2-resident; no Xb LDS buffer).
// Per group: B: vB[n,col] = MA'[n,j]*x + cq (C-in);
//   scan: 8-chunk Kogge-Stone via dpp row_shr2/4/8 (parity-preserving:
//     i1=v+a*shr2(v); i2=i1+a2*shr4(i1); i3=i2+a4*shr8(i2); e=shr2(i3);
//     se = a^c*sig0 + e; sig0' = a^8*sig0 + bcast(i3@c=7) via swz or14);
//   D: y = CAT x Sig + TG x Xb (C-in = Hcp; Dw*x folded into TG diagonal)
//     -> gelu -> per-lane pool -> per-wave shfl reduce -> fused atomic head.
// MFMA 16x16x32 bf16 layouts (verified m89/m91): A[m=lane&15][k=quad*8+j],
// B[k=quad*8+j][n=lane&15], D: col=lane&15, row=quad*4+reg.
__global__ __launch_bounds__(256, 3) void ssm_mfma_kernel(
    const float* __restrict__ x,      // [B, T]
    const float* __restrict__ w_in,   // [D]
    const float* __restrict__ b_in,   // [D]
    const float* __restrict__ A_diag, // [D, 64]
    const float* __restrict__ B_in,   // [D, 64]
    const float* __restrict__ C_out,  // [D, 64]
    const float* __restrict__ D_skip, // [D]
    const float* __restrict__ W_head, // [2D, NCLS]
    const float* __restrict__ b_head, // [NCLS]
    float* __restrict__ out)          // [B, NCLS] (pre-zeroed, atomic accum)
{
    // Sigb (64 rows x 72, 9216 B) unioned with Pow[65*64] (16640 B, setup)
    __shared__ __align__(16) unsigned char PSbuf[65 * 64 * 4];
    __shared__ unsigned short MAb [64 * 72];
    __shared__ unsigned short CATb[64 * 72];
    __shared__ unsigned short TGb [64 * 72];
    __shared__ float Pf[64], Qf[64], Gf[64], Hf[64], HcpS[64], Anf[64], cqS[64];

    unsigned short* Sigb = (unsigned short*)PSbuf;   // [64*72] main loop
    float*          Pow  = (float*)PSbuf;            // [65*64] setup only

    const int tid  = threadIdx.x;
    const int lane = tid & 63;
    const int wid  = tid >> 6;            // 0..3
    const int m16  = lane & 15;
    const int q    = lane >> 4;
    const int q4   = q * 4;
    const int q8   = q * 8;
    const int d    = blockIdx.x >> 2;
    const int quarter = blockIdx.x & 3;

    const int pcol = wid * 16 + m16;      // wave-private Sigb row (0..63)
    const int cch  = m16 >> 1;            // chunk index 0..7
    const bool cc1 = (cch & 1) != 0;
    const bool cc2 = (cch & 2) != 0;
    const bool cc4 = (cch & 4) != 0;

    const float wd = w_in[d], bd = b_in[d];
    const float Dw = D_skip[d] * wd;
    const float Db = D_skip[d] * bd;

    // direct-load geometry: lane (m16,q) -> x[b, g*512 + c*64 + q8 + j]
    const int bglob = quarter * 8 + wid * 2 + (m16 & 1);
    const float* xrow = x + bglob * SEQ + cch * 64 + q * 8;

    // issue group-0 loads immediately; setup hides the latency
    float4 xa = ((const float4*)xrow)[0];         // j = q8+0..3
    float4 xb = ((const float4*)xrow)[1];         // j = q8+4..7
    float4 xc = ((const float4*)(xrow + 32))[0];  // j = 32+q8+0..3
    float4 xd = ((const float4*)(xrow + 32))[1];  // j = 32+q8+4..7

    // ---- setup 1: per-n tables + power table (wave 0) ----
    if (tid < 64) {
        const int n = tid;
        const float An = A_diag[d * 64 + n];
        const float CB = B_in[d * 64 + n] * C_out[d * 64 + n];
        Anf[n] = An; Pf[n] = CB * wd; Qf[n] = CB * bd;
        float p = 1.0f;
        for (int m = 0; m <= 64; ++m) { Pow[m * 64 + n] = p; p *= An; }
    }
    __syncthreads();
    // ---- setup 2: G/H = Pow x {P,Q} matvec, 4 threads per row ----
    {
        const int mrow = tid >> 2, p16 = (tid & 3) * 16;
        float g = 0.0f, h = 0.0f;
        #pragma unroll
        for (int jj = 0; jj < 16; ++jj) {
            const float pw = Pow[mrow * 64 + p16 + jj];
            g = fmaf(pw, Pf[p16 + jj], g);
            h = fmaf(pw, Qf[p16 + jj], h);
        }
        g += __shfl_xor(g, 1, 64); g += __shfl_xor(g, 2, 64);
        h += __shfl_xor(h, 1, 64); h += __shfl_xor(h, 2, 64);
        if ((tid & 3) == 0) { Gf[mrow] = g; Hf[mrow] = h; }
    }
    __syncthreads();
    // ---- setup 3: MA'/CAT/TG matrices + Hcp prefix + cq ----
    {
        const int r0 = tid >> 2, c0 = (tid & 3) * 16;
        #pragma unroll
        for (int jj = 0; jj < 16; ++jj) {
            const int j = c0 + jj;
            MAb [r0 * 72 + j] = f2bs(Pf[r0] * Pow[(63 - j) * 64 + r0]);
            CATb[r0 * 72 + j] = f2bs(Pow[(r0 + 1) * 64 + j]);
            TGb [r0 * 72 + j] = (j < r0)  ? f2bs(Gf[r0 - j])
                              : (j == r0) ? f2bs(Gf[0] + Dw)   // Dw*x folded in
                                          : (unsigned short)0;
        }
        if (tid < 64) {
            float v = Hf[tid];
            #pragma unroll
            for (int dl = 1; dl < 64; dl <<= 1) {
                const float t = __shfl(v, (tid - dl) & 63, 64);
                v += (tid >= dl) ? t : 0.0f;
            }
            HcpS[tid] = v + Db;
            const float A64 = Pow[64 * 64 + tid];
            cqS[tid] = Qf[tid] * (1.0f - A64) / (1.0f - Anf[tid]);
        }
    }
    __syncthreads();

    // ---- loop-invariant regs: MA' frags (32) + a64 (16) + a^c (16) ----
    s8v aMA[4][2];
    #pragma unroll
    for (int rt = 0; rt < 4; ++rt)
        #pragma unroll
        for (int kb = 0; kb < 2; ++kb)
            aMA[rt][kb] = *(const s8v*)&MAb[(rt * 16 + m16) * 72 + kb * 32 + q8];
    float a64v[4][4], acv[4][4], sig0[4][4];
    #pragma unroll
    for (int rt = 0; rt < 4; ++rt)
        #pragma unroll
        for (int r = 0; r < 4; ++r) {
            const float a = Pow[64 * 64 + rt * 16 + q4 + r];  // last Pow read
            const float a2 = a * a;
            a64v[rt][r] = a;
            acv [rt][r] = (cc1 ? a : 1.0f) * (cc2 ? a2 : 1.0f)
                        * (cc4 ? a2 * a2 : 1.0f);             // a^c, c=cch
            sig0[rt][r] = 0.0f;
        }
    __syncthreads();   // Pow reads done before scan overwrites Sigb

    // ---- prologue: pack group-0 B-frags in registers ----
    s8v bx0, bx1;
    bx0[0]=(short)f2bs(xa.x); bx0[1]=(short)f2bs(xa.y);
    bx0[2]=(short)f2bs(xa.z); bx0[3]=(short)f2bs(xa.w);
    bx0[4]=(short)f2bs(xb.x); bx0[5]=(short)f2bs(xb.y);
    bx0[6]=(short)f2bs(xb.z); bx0[7]=(short)f2bs(xb.w);
    bx1[0]=(short)f2bs(xc.x); bx1[1]=(short)f2bs(xc.y);
    bx1[2]=(short)f2bs(xc.z); bx1[3]=(short)f2bs(xc.w);
    bx1[4]=(short)f2bs(xd.x); bx1[5]=(short)f2bs(xd.y);
    bx1[6]=(short)f2bs(xd.z); bx1[7]=(short)f2bs(xd.w);

    float psum = 0.0f, pmax = -1e30f;

    #pragma unroll 1
    for (int g = 0; g < 8; ++g) {
        // issue-early loads for group g+1 (drain covered by whole body)
        float4 ya, yb, yc, yd;
        if (g < 7) {
            const float* xg = xrow + (g + 1) * 512;
            ya = ((const float4*)xg)[0];
            yb = ((const float4*)xg)[1];
            yc = ((const float4*)(xg + 32))[0];
            yd = ((const float4*)(xg + 32))[1];
        }
        // ---- B: vB = cq + MA' x Xb ----
        f4v vB[4];
        __builtin_amdgcn_s_setprio(1);
        #pragma unroll
        for (int rt = 0; rt < 4; ++rt) {
            const f4v cqv = *(const f4v*)&cqS[rt * 16 + q4];
            f4v t = __builtin_amdgcn_mfma_f32_16x16x32_bf16(aMA[rt][0], bx0, cqv, 0, 0, 0);
            vB[rt] = __builtin_amdgcn_mfma_f32_16x16x32_bf16(aMA[rt][1], bx1, t, 0, 0, 0);
        }
        __builtin_amdgcn_s_setprio(0);
        // ---- in-wave 8-chunk scan (parity-preserving DPP Kogge-Stone) ----
        #pragma unroll
        for (int rt = 0; rt < 4; ++rt) {
            u4v sg;
            #pragma unroll
            for (int r = 0; r < 4; ++r) {
                const float a  = a64v[rt][r];
                const float a2 = a * a, a4 = a2 * a2;
                const float v  = vB[rt][r];
                const float i1 = fmaf(a,  dpp_shr2(v),  v);
                const float i2 = fmaf(a2, dpp_shr4(i1), i1);
                const float i3 = fmaf(a4, dpp_shr8(i2), i2);
                const float e  = dpp_shr2(i3);                 // i_{c-1}
                const float se = fmaf(acv[rt][r], sig0[rt][r], e);
                const float S  = swz_or14(i3);                 // bcast c=7
                sig0[rt][r] = fmaf(a4 * a4, sig0[rt][r], S);   // A^512 advance
                sg[r] = f2bs(se);
            }
            *(u4v*)&Sigb[pcol * 72 + rt * 16 + q4] = sg;
        }
        const s8v bs0 = *(const s8v*)&Sigb[pcol * 72 + q8];
        const s8v bs1 = *(const s8v*)&Sigb[pcol * 72 + 32 + q8];
        // ---- D: y = Hcp + CAT x Sig + TG x Xb -> gelu -> pool ----
        #pragma unroll
        for (int rt = 0; rt < 4; ++rt) {
            const int ro = (rt * 16 + m16) * 72 + q8;
            const f4v hcpv = *(const f4v*)&HcpS[rt * 16 + q4];
            __builtin_amdgcn_s_setprio(1);
            f4v acc = __builtin_amdgcn_mfma_f32_16x16x32_bf16(
                          *(const s8v*)&CATb[ro], bs0, hcpv, 0, 0, 0);
            acc = __builtin_amdgcn_mfma_f32_16x16x32_bf16(
                          *(const s8v*)&CATb[ro + 32], bs1, acc, 0, 0, 0);
            acc = __builtin_amdgcn_mfma_f32_16x16x32_bf16(
                          *(const s8v*)&TGb[ro], bx0, acc, 0, 0, 0);
            acc = __builtin_amdgcn_mfma_f32_16x16x32_bf16(
                          *(const s8v*)&TGb[ro + 32], bx1, acc, 0, 0, 0);
            __builtin_amdgcn_s_setprio(0);
            #pragma unroll
            for (int r = 0; r < 4; ++r) {
                const float yt = acc[r];
                const float y2 = yt * yt;
                const float zn = yt * fmaf(-0.10294272f, y2, -2.30220437f);
                const float h  = yt * __builtin_amdgcn_rcpf(1.0f + exp2f(zn));
                psum += h;
                pmax = fmaxf(pmax, h);
            }
        }
        // ---- rotate prefetch into B-frags for g+1 ----
        if (g < 7) {
            bx0[0]=(short)f2bs(ya.x); bx0[1]=(short)f2bs(ya.y);
            bx0[2]=(short)f2bs(ya.z); bx0[3]=(short)f2bs(ya.w);
            bx0[4]=(short)f2bs(yb.x); bx0[5]=(short)f2bs(yb.y);
            bx0[6]=(short)f2bs(yb.z); bx0[7]=(short)f2bs(yb.w);
            bx1[0]=(short)f2bs(yc.x); bx1[1]=(short)f2bs(yc.y);
            bx1[2]=(short)f2bs(yc.z); bx1[3]=(short)f2bs(yc.w);
            bx1[4]=(short)f2bs(yd.x); bx1[5]=(short)f2bs(yd.y);
            bx1[6]=(short)f2bs(yd.z); bx1[7]=(short)f2bs(yd.w);
        }
    }

    // ---- pool: reduce across lanes sharing parity (b_loc = lane&1) ----
    #pragma unroll
    for (int dl = 2; dl <= 32; dl <<= 1) {
        psum += __shfl_xor(psum, dl, 64);
        pmax  = fmaxf(pmax, __shfl_xor(pmax, dl, 64));
    }
    // ---- fused head: out[b,c] += avg*W[d,c] + max*W[D+d,c] (+bias once) ----
    if (lane < 2) {
        const int bg = quarter * 8 + wid * 2 + lane;
        const float s  = psum * (1.0f / SEQ);
        #pragma unroll
        for (int c = 0; c < NCLS; ++c) {
            float contrib = s    * W_head[d * NCLS + c]
                          + pmax * W_head[(DMODEL + d) * NCLS + c];
            if (d == 0) contrib += b_head[c];   // each (b,c) gets bias once
            atomicAdd(&out[bg * NCLS + c], contrib);
        }
    }
}

extern "C" void kernel_launch(void* const* d_in, const int* in_sizes, int n_in,
                              void* d_out, int out_size, void* d_ws, size_t ws_size,
                              hipStream_t stream) {
    const float* x      = (const float*)d_in[0];
    const float* w_in   = (const float*)d_in[1];
    const float* b_in   = (const float*)d_in[2];
    const float* A_diag = (const float*)d_in[3];
    const float* B_in   = (const float*)d_in[4];
    const float* C_out  = (const float*)d_in[5];
    const float* D_skip = (const float*)d_in[6];
    const float* W_head = (const float*)d_in[7];
    const float* b_head = (const float*)d_in[8];
    float* out = (float*)d_out;

    hipMemsetAsync(out, 0, BATCH * NCLS * sizeof(float), stream);
    ssm_mfma_kernel<<<DMODEL * 4, 256, 0, stream>>>(x, w_in, b_in, A_diag, B_in,
                                                    C_out, D_skip, W_head, b_head, out);
}

// Round 6
// 178.184 us; speedup vs baseline: 1.5968x; 1.5968x over previous
//
#include <hip/hip_runtime.h>
#include <hip/hip_bf16.h>

#define BATCH 32
#define SEQ 4096
#define DMODEL 256
#define NCLS 5

typedef short          s8v  __attribute__((ext_vector_type(8)));  // 8 bf16 frag
typedef unsigned short u4v  __attribute__((ext_vector_type(4)));
typedef float          f4v  __attribute__((ext_vector_type(4)));  // C/D frag

// RNE fp32->bf16 via compiler path (fuses to v_cvt_pk_bf16_f32, m240)
__device__ __forceinline__ unsigned short f2bs(float f) {
    __hip_bfloat16 h = __float2bfloat16(f);
    return *reinterpret_cast<unsigned short*>(&h);
}
// DPP row_shr within 16-lane rows, 0-fill (bound_ctrl)
__device__ __forceinline__ float dpp_shr2(float v) {
    return __int_as_float(__builtin_amdgcn_update_dpp(
        0, __float_as_int(v), 0x112, 0xF, 0xF, true));
}
__device__ __forceinline__ float dpp_shr4(float v) {
    return __int_as_float(__builtin_amdgcn_update_dpp(
        0, __float_as_int(v), 0x114, 0xF, 0xF, true));
}
__device__ __forceinline__ float dpp_shr8(float v) {
    return __int_as_float(__builtin_amdgcn_update_dpp(
        0, __float_as_int(v), 0x118, 0xF, 0xF, true));
}
// ds_swizzle BitMode: lane -> lane|14 (broadcast c=7 lane of each parity pair)
__device__ __forceinline__ float swz_or14(float v) {
    return __int_as_float(__builtin_amdgcn_ds_swizzle(
        __float_as_int(v), 0x01DF));
}

// R5 post-mortem: (256,3) gave VGPR cap 85 (6 waves/EU) -> ~65-reg spill,
// 108MB scratch writes. Empirical launch-bounds rule on this toolchain
// (fits (512,4)->64, (512,2)->128, (256,3)->85): effective waves/EU =
// 2 x arg2, REGARDLESS of block size; cap = 512/(2*arg2).
// => (256,2) -> cap 128 (and also safe under the CUDA blocks/CU reading).
//
// Occupancy plan: block = 256 thr (4 waves); LDS cut to 37.1KB (MAb LDS
// array eliminated -- A-frags built directly from Pf x Pow in setup) ->
// 4 blocks/CU x 4 waves = 16 waves/CU = 4 waves/EU (2x R1). Grid 1024 =
// 256 d x 4 batch-quarters = exactly full residency.
// Live-set diet to fit cap 128 (~110 peak): acv recomputed per group,
// a64 demoted to LDS table A64S (f4v read per rt per group).
//
// Wave owns 2 batches x 8 chunks (col m16 -> b_loc=m16&1, c=m16>>1);
// 8 groups of 512 timesteps; ZERO main-loop barriers (all LDS traffic
// wave-private; in-order DS pipe). Only MA' fragments live in regs;
// CAT/TG/cq/hcp re-read from LDS per group. x loads go DIRECTLY
// global->B-frags (x is L2-resident; no Xb LDS buffer).
// Per group: B: vB[n,col] = MA'[n,j]*x + cq (C-in);
//   scan: 8-chunk Kogge-Stone via dpp row_shr2/4/8 (parity-preserving:
//     i1=v+a*shr2(v); i2=i1+a2*shr4(i1); i3=i2+a4*shr8(i2); e=shr2(i3);
//     se = a^c*sig0 + e; sig0' = a^8*sig0 + bcast(i3@c=7) via swz or14);
//   D: y = CAT x Sig + TG x Xb (C-in = Hcp; Dw*x folded into TG diagonal)
//     -> gelu -> per-lane pool -> per-wave shfl reduce -> fused atomic head.
// MFMA 16x16x32 bf16 layouts (verified m89/m91): A[m=lane&15][k=quad*8+j],
// B[k=quad*8+j][n=lane&15], D: col=lane&15, row=quad*4+reg.
__global__ __launch_bounds__(256, 2) void ssm_mfma_kernel(
    const float* __restrict__ x,      // [B, T]
    const float* __restrict__ w_in,   // [D]
    const float* __restrict__ b_in,   // [D]
    const float* __restrict__ A_diag, // [D, 64]
    const float* __restrict__ B_in,   // [D, 64]
    const float* __restrict__ C_out,  // [D, 64]
    const float* __restrict__ D_skip, // [D]
    const float* __restrict__ W_head, // [2D, NCLS]
    const float* __restrict__ b_head, // [NCLS]
    float* __restrict__ out)          // [B, NCLS] (pre-zeroed, atomic accum)
{
    // Sigb (64x72 shorts, 9216 B) unioned with Pow[65*64] f32 (16640 B, setup)
    __shared__ __align__(16) unsigned char PSbuf[65 * 64 * 4];
    __shared__ unsigned short CATb[64 * 72];
    __shared__ unsigned short TGb [64 * 72];
    __shared__ float Pf[64], Qf[64], Gf[64], Hf[64], HcpS[64], Anf[64];
    __shared__ float cqS[64], A64S[64];

    unsigned short* Sigb = (unsigned short*)PSbuf;   // [64*72] main loop
    float*          Pow  = (float*)PSbuf;            // [65*64] setup only

    const int tid  = threadIdx.x;
    const int lane = tid & 63;
    const int wid  = tid >> 6;            // 0..3
    const int m16  = lane & 15;
    const int q    = lane >> 4;
    const int q4   = q * 4;
    const int q8   = q * 8;
    const int d    = blockIdx.x >> 2;
    const int quarter = blockIdx.x & 3;

    const int pcol = wid * 16 + m16;      // wave-private Sigb row (0..63)
    const int cch  = m16 >> 1;            // chunk index 0..7
    const bool cc1 = (cch & 1) != 0;
    const bool cc2 = (cch & 2) != 0;
    const bool cc4 = (cch & 4) != 0;

    const float wd = w_in[d], bd = b_in[d];
    const float Dw = D_skip[d] * wd;
    const float Db = D_skip[d] * bd;

    // direct-load geometry: lane (m16,q) -> x[b, g*512 + c*64 + q8 + j]
    const int bglob = quarter * 8 + wid * 2 + (m16 & 1);
    const float* xrow = x + bglob * SEQ + cch * 64 + q * 8;

    // issue group-0 loads immediately; setup hides the latency
    float4 xa = ((const float4*)xrow)[0];         // j = q8+0..3
    float4 xb = ((const float4*)xrow)[1];         // j = q8+4..7
    float4 xc = ((const float4*)(xrow + 32))[0];  // j = 32+q8+0..3
    float4 xd = ((const float4*)(xrow + 32))[1];  // j = 32+q8+4..7

    // ---- setup 1: per-n tables + power table (wave 0) ----
    if (tid < 64) {
        const int n = tid;
        const float An = A_diag[d * 64 + n];
        const float CB = B_in[d * 64 + n] * C_out[d * 64 + n];
        Anf[n] = An; Pf[n] = CB * wd; Qf[n] = CB * bd;
        float p = 1.0f;
        for (int m = 0; m <= 64; ++m) { Pow[m * 64 + n] = p; p *= An; }
    }
    __syncthreads();
    // ---- setup 2: G/H = Pow x {P,Q} matvec, 4 threads per row ----
    {
        const int mrow = tid >> 2, p16 = (tid & 3) * 16;
        float g = 0.0f, h = 0.0f;
        #pragma unroll
        for (int jj = 0; jj < 16; ++jj) {
            const float pw = Pow[mrow * 64 + p16 + jj];
            g = fmaf(pw, Pf[p16 + jj], g);
            h = fmaf(pw, Qf[p16 + jj], h);
        }
        g += __shfl_xor(g, 1, 64); g += __shfl_xor(g, 2, 64);
        h += __shfl_xor(h, 1, 64); h += __shfl_xor(h, 2, 64);
        if ((tid & 3) == 0) { Gf[mrow] = g; Hf[mrow] = h; }
    }
    __syncthreads();
    // ---- setup 3: CAT/TG matrices + Hcp prefix + cq + A64 table ----
    {
        const int r0 = tid >> 2, c0 = (tid & 3) * 16;
        #pragma unroll
        for (int jj = 0; jj < 16; ++jj) {
            const int j = c0 + jj;
            CATb[r0 * 72 + j] = f2bs(Pow[(r0 + 1) * 64 + j]);
            TGb [r0 * 72 + j] = (j < r0)  ? f2bs(Gf[r0 - j])
                              : (j == r0) ? f2bs(Gf[0] + Dw)   // Dw*x folded in
                                          : (unsigned short)0;
        }
        if (tid < 64) {
            float v = Hf[tid];
            #pragma unroll
            for (int dl = 1; dl < 64; dl <<= 1) {
                const float t = __shfl(v, (tid - dl) & 63, 64);
                v += (tid >= dl) ? t : 0.0f;
            }
            HcpS[tid] = v + Db;
            const float A64 = Pow[64 * 64 + tid];
            A64S[tid] = A64;
            cqS[tid]  = Qf[tid] * (1.0f - A64) / (1.0f - Anf[tid]);
        }
    }
    __syncthreads();

    // ---- loop-invariant regs: ONLY MA' fragments (32), built from Pow ----
    s8v aMA[4][2];
    #pragma unroll
    for (int rt = 0; rt < 4; ++rt) {
        const int n = rt * 16 + m16;
        const float pn = Pf[n];
        #pragma unroll
        for (int kb = 0; kb < 2; ++kb) {
            s8v f;
            #pragma unroll
            for (int jj = 0; jj < 8; ++jj) {
                const int j = kb * 32 + q8 + jj;
                f[jj] = (short)f2bs(pn * Pow[(63 - j) * 64 + n]);
            }
            aMA[rt][kb] = f;
        }
    }
    float sig0[4][4];
    #pragma unroll
    for (int rt = 0; rt < 4; ++rt)
        #pragma unroll
        for (int r = 0; r < 4; ++r) sig0[rt][r] = 0.0f;
    __syncthreads();   // Pow reads done before scan overwrites Sigb

    // ---- prologue: pack group-0 B-frags in registers ----
    s8v bx0, bx1;
    bx0[0]=(short)f2bs(xa.x); bx0[1]=(short)f2bs(xa.y);
    bx0[2]=(short)f2bs(xa.z); bx0[3]=(short)f2bs(xa.w);
    bx0[4]=(short)f2bs(xb.x); bx0[5]=(short)f2bs(xb.y);
    bx0[6]=(short)f2bs(xb.z); bx0[7]=(short)f2bs(xb.w);
    bx1[0]=(short)f2bs(xc.x); bx1[1]=(short)f2bs(xc.y);
    bx1[2]=(short)f2bs(xc.z); bx1[3]=(short)f2bs(xc.w);
    bx1[4]=(short)f2bs(xd.x); bx1[5]=(short)f2bs(xd.y);
    bx1[6]=(short)f2bs(xd.z); bx1[7]=(short)f2bs(xd.w);

    float psum = 0.0f, pmax = -1e30f;

    #pragma unroll 1
    for (int g = 0; g < 8; ++g) {
        // issue-early loads for group g+1 (drain covered by whole body)
        float4 ya, yb, yc, yd;
        if (g < 7) {
            const float* xg = xrow + (g + 1) * 512;
            ya = ((const float4*)xg)[0];
            yb = ((const float4*)xg)[1];
            yc = ((const float4*)(xg + 32))[0];
            yd = ((const float4*)(xg + 32))[1];
        }
        // ---- B: vB = cq + MA' x Xb ----
        f4v vB[4];
        __builtin_amdgcn_s_setprio(1);
        #pragma unroll
        for (int rt = 0; rt < 4; ++rt) {
            const f4v cqv = *(const f4v*)&cqS[rt * 16 + q4];
            f4v t = __builtin_amdgcn_mfma_f32_16x16x32_bf16(aMA[rt][0], bx0, cqv, 0, 0, 0);
            vB[rt] = __builtin_amdgcn_mfma_f32_16x16x32_bf16(aMA[rt][1], bx1, t, 0, 0, 0);
        }
        __builtin_amdgcn_s_setprio(0);
        // ---- in-wave 8-chunk scan (parity-preserving DPP Kogge-Stone) ----
        #pragma unroll
        for (int rt = 0; rt < 4; ++rt) {
            const f4v a64q = *(const f4v*)&A64S[rt * 16 + q4];
            u4v sg;
            #pragma unroll
            for (int r = 0; r < 4; ++r) {
                const float a  = a64q[r];
                const float a2 = a * a, a4 = a2 * a2;
                const float acv = (cc1 ? a : 1.0f) * (cc2 ? a2 : 1.0f)
                                * (cc4 ? a4 : 1.0f);           // a^c, recomputed
                const float v  = vB[rt][r];
                const float i1 = fmaf(a,  dpp_shr2(v),  v);
                const float i2 = fmaf(a2, dpp_shr4(i1), i1);
                const float i3 = fmaf(a4, dpp_shr8(i2), i2);
                const float e  = dpp_shr2(i3);                 // i_{c-1}
                const float se = fmaf(acv, sig0[rt][r], e);
                const float S  = swz_or14(i3);                 // bcast c=7
                sig0[rt][r] = fmaf(a4 * a4, sig0[rt][r], S);   // A^512 advance
                sg[r] = f2bs(se);
            }
            *(u4v*)&Sigb[pcol * 72 + rt * 16 + q4] = sg;
        }
        const s8v bs0 = *(const s8v*)&Sigb[pcol * 72 + q8];
        const s8v bs1 = *(const s8v*)&Sigb[pcol * 72 + 32 + q8];
        // ---- D: y = Hcp + CAT x Sig + TG x Xb -> gelu -> pool ----
        #pragma unroll
        for (int rt = 0; rt < 4; ++rt) {
            const int ro = (rt * 16 + m16) * 72 + q8;
            const f4v hcpv = *(const f4v*)&HcpS[rt * 16 + q4];
            __builtin_amdgcn_s_setprio(1);
            f4v acc = __builtin_amdgcn_mfma_f32_16x16x32_bf16(
                          *(const s8v*)&CATb[ro], bs0, hcpv, 0, 0, 0);
            acc = __builtin_amdgcn_mfma_f32_16x16x32_bf16(
                          *(const s8v*)&CATb[ro + 32], bs1, acc, 0, 0, 0);
            acc = __builtin_amdgcn_mfma_f32_16x16x32_bf16(
                          *(const s8v*)&TGb[ro], bx0, acc, 0, 0, 0);
            acc = __builtin_amdgcn_mfma_f32_16x16x32_bf16(
                          *(const s8v*)&TGb[ro + 32], bx1, acc, 0, 0, 0);
            __builtin_amdgcn_s_setprio(0);
            #pragma unroll
            for (int r = 0; r < 4; ++r) {
                const float yt = acc[r];
                const float y2 = yt * yt;
                const float zn = yt * fmaf(-0.10294272f, y2, -2.30220437f);
                const float h  = yt * __builtin_amdgcn_rcpf(1.0f + exp2f(zn));
                psum += h;
                pmax = fmaxf(pmax, h);
            }
        }
        // ---- rotate prefetch into B-frags for g+1 ----
        if (g < 7) {
            bx0[0]=(short)f2bs(ya.x); bx0[1]=(short)f2bs(ya.y);
            bx0[2]=(short)f2bs(ya.z); bx0[3]=(short)f2bs(ya.w);
            bx0[4]=(short)f2bs(yb.x); bx0[5]=(short)f2bs(yb.y);
            bx0[6]=(short)f2bs(yb.z); bx0[7]=(short)f2bs(yb.w);
            bx1[0]=(short)f2bs(yc.x); bx1[1]=(short)f2bs(yc.y);
            bx1[2]=(short)f2bs(yc.z); bx1[3]=(short)f2bs(yc.w);
            bx1[4]=(short)f2bs(yd.x); bx1[5]=(short)f2bs(yd.y);
            bx1[6]=(short)f2bs(yd.z); bx1[7]=(short)f2bs(yd.w);
        }
    }

    // ---- pool: reduce across lanes sharing parity (b_loc = lane&1) ----
    #pragma unroll
    for (int dl = 2; dl <= 32; dl <<= 1) {
        psum += __shfl_xor(psum, dl, 64);
        pmax  = fmaxf(pmax, __shfl_xor(pmax, dl, 64));
    }
    // ---- fused head: out[b,c] += avg*W[d,c] + max*W[D+d,c] (+bias once) ----
    if (lane < 2) {
        const int bg = quarter * 8 + wid * 2 + lane;
        const float s  = psum * (1.0f / SEQ);
        #pragma unroll
        for (int c = 0; c < NCLS; ++c) {
            float contrib = s    * W_head[d * NCLS + c]
                          + pmax * W_head[(DMODEL + d) * NCLS + c];
            if (d == 0) contrib += b_head[c];   // each (b,c) gets bias once
            atomicAdd(&out[bg * NCLS + c], contrib);
        }
    }
}

extern "C" void kernel_launch(void* const* d_in, const int* in_sizes, int n_in,
                              void* d_out, int out_size, void* d_ws, size_t ws_size,
                              hipStream_t stream) {
    const float* x      = (const float*)d_in[0];
    const float* w_in   = (const float*)d_in[1];
    const float* b_in   = (const float*)d_in[2];
    const float* A_diag = (const float*)d_in[3];
    const float* B_in   = (const float*)d_in[4];
    const float* C_out  = (const float*)d_in[5];
    const float* D_skip = (const float*)d_in[6];
    const float* W_head = (const float*)d_in[7];
    const float* b_head = (const float*)d_in[8];
    float* out = (float*)d_out;

    hipMemsetAsync(out, 0, BATCH * NCLS * sizeof(float), stream);
    ssm_mfma_kernel<<<DMODEL * 4, 256, 0, stream>>>(x, w_in, b_in, A_diag, B_in,
                                                    C_out, D_skip, W_head, b_head, out);
}

// Round 7
// 170.901 us; speedup vs baseline: 1.6648x; 1.0426x over previous
//
#include <hip/hip_runtime.h>
#include <hip/hip_bf16.h>

#define BATCH 32
#define SEQ 4096
#define DMODEL 256
#define NCLS 5

typedef short          s8v  __attribute__((ext_vector_type(8)));  // 8 bf16 frag
typedef unsigned short u4v  __attribute__((ext_vector_type(4)));
typedef float          f4v  __attribute__((ext_vector_type(4)));  // C/D frag

// RNE fp32->bf16 via compiler path (fuses to v_cvt_pk_bf16_f32, m240)
__device__ __forceinline__ unsigned short f2bs(float f) {
    __hip_bfloat16 h = __float2bfloat16(f);
    return *reinterpret_cast<unsigned short*>(&h);
}
// DPP row_shr within 16-lane rows, 0-fill (bound_ctrl)
__device__ __forceinline__ float dpp_shr2(float v) {
    return __int_as_float(__builtin_amdgcn_update_dpp(
        0, __float_as_int(v), 0x112, 0xF, 0xF, true));
}
__device__ __forceinline__ float dpp_shr4(float v) {
    return __int_as_float(__builtin_amdgcn_update_dpp(
        0, __float_as_int(v), 0x114, 0xF, 0xF, true));
}
__device__ __forceinline__ float dpp_shr8(float v) {
    return __int_as_float(__builtin_amdgcn_update_dpp(
        0, __float_as_int(v), 0x118, 0xF, 0xF, true));
}
// ds_swizzle BitMode: lane -> lane|14 (broadcast c=7 lane of each parity pair)
__device__ __forceinline__ float swz_or14(float v) {
    return __int_as_float(__builtin_amdgcn_ds_swizzle(
        __float_as_int(v), 0x01DF));
}

// R6 post-mortem: cap 128 held (VGPR_Count=128) but live set ~150 -> STILL
// spilled (22MB scratch). Three rounds confirm: this algorithm needs ~150
// regs; any cap below that spills. Fallback (pre-committed): UNCAPPED
// allocation -> ~150-170 regs -> 3 waves/SIMD naturally (VGPR ladder
// halves at 64/128/256, m69), zero spill. LDS 37.4KB x 3 blocks/CU fits
// 160KB; main loop is barrier-free so cross-block overlap is real.
// Also: B-phase MFMA fused with scan per-rt (vB consumed immediately) to
// shrink the register-coloring window.
//
// Block = 256 thr (4 waves), grid 1024 = 256 d x 4 batch-quarters.
// Wave owns 2 batches x 8 chunks (col m16 -> b_loc=m16&1, c=m16>>1);
// 8 groups of 512 timesteps; ZERO main-loop barriers (all LDS traffic
// wave-private; in-order DS pipe). Only MA' fragments live in regs;
// CAT/TG/cq/hcp re-read from LDS per group. x loads go DIRECTLY
// global->B-frags (x is L2-resident; no Xb LDS buffer).
// Per group, per rt: vB = cq + MA' x Xb (MFMA);
//   scan: 8-chunk Kogge-Stone via dpp row_shr2/4/8 (parity-preserving:
//     i1=v+a*shr2(v); i2=i1+a2*shr4(i1); i3=i2+a4*shr8(i2); e=shr2(i3);
//     se = a^c*sig0 + e; sig0' = a^8*sig0 + bcast(i3@c=7) via swz or14);
//   then D: y = CAT x Sig + TG x Xb (C-in = Hcp; Dw*x folded into TG diag)
//     -> gelu -> per-lane pool -> per-wave shfl reduce -> fused atomic head.
// MFMA 16x16x32 bf16 layouts (verified m89/m91): A[m=lane&15][k=quad*8+j],
// B[k=quad*8+j][n=lane&15], D: col=lane&15, row=quad*4+reg.
__global__ __launch_bounds__(256) void ssm_mfma_kernel(
    const float* __restrict__ x,      // [B, T]
    const float* __restrict__ w_in,   // [D]
    const float* __restrict__ b_in,   // [D]
    const float* __restrict__ A_diag, // [D, 64]
    const float* __restrict__ B_in,   // [D, 64]
    const float* __restrict__ C_out,  // [D, 64]
    const float* __restrict__ D_skip, // [D]
    const float* __restrict__ W_head, // [2D, NCLS]
    const float* __restrict__ b_head, // [NCLS]
    float* __restrict__ out)          // [B, NCLS] (pre-zeroed, atomic accum)
{
    // Sigb (64x72 shorts, 9216 B) unioned with Pow[65*64] f32 (16640 B, setup)
    __shared__ __align__(16) unsigned char PSbuf[65 * 64 * 4];
    __shared__ unsigned short CATb[64 * 72];
    __shared__ unsigned short TGb [64 * 72];
    __shared__ float Pf[64], Qf[64], Gf[64], Hf[64], HcpS[64], Anf[64];
    __shared__ float cqS[64], A64S[64];

    unsigned short* Sigb = (unsigned short*)PSbuf;   // [64*72] main loop
    float*          Pow  = (float*)PSbuf;            // [65*64] setup only

    const int tid  = threadIdx.x;
    const int lane = tid & 63;
    const int wid  = tid >> 6;            // 0..3
    const int m16  = lane & 15;
    const int q    = lane >> 4;
    const int q4   = q * 4;
    const int q8   = q * 8;
    const int d    = blockIdx.x >> 2;
    const int quarter = blockIdx.x & 3;

    const int pcol = wid * 16 + m16;      // wave-private Sigb row (0..63)
    const int cch  = m16 >> 1;            // chunk index 0..7
    const bool cc1 = (cch & 1) != 0;
    const bool cc2 = (cch & 2) != 0;
    const bool cc4 = (cch & 4) != 0;

    const float wd = w_in[d], bd = b_in[d];
    const float Dw = D_skip[d] * wd;
    const float Db = D_skip[d] * bd;

    // direct-load geometry: lane (m16,q) -> x[b, g*512 + c*64 + q8 + j]
    const int bglob = quarter * 8 + wid * 2 + (m16 & 1);
    const float* xrow = x + bglob * SEQ + cch * 64 + q * 8;

    // issue group-0 loads immediately; setup hides the latency
    float4 xa = ((const float4*)xrow)[0];         // j = q8+0..3
    float4 xb = ((const float4*)xrow)[1];         // j = q8+4..7
    float4 xc = ((const float4*)(xrow + 32))[0];  // j = 32+q8+0..3
    float4 xd = ((const float4*)(xrow + 32))[1];  // j = 32+q8+4..7

    // ---- setup 1: per-n tables + power table (wave 0) ----
    if (tid < 64) {
        const int n = tid;
        const float An = A_diag[d * 64 + n];
        const float CB = B_in[d * 64 + n] * C_out[d * 64 + n];
        Anf[n] = An; Pf[n] = CB * wd; Qf[n] = CB * bd;
        float p = 1.0f;
        for (int m = 0; m <= 64; ++m) { Pow[m * 64 + n] = p; p *= An; }
    }
    __syncthreads();
    // ---- setup 2: G/H = Pow x {P,Q} matvec, 4 threads per row ----
    {
        const int mrow = tid >> 2, p16 = (tid & 3) * 16;
        float g = 0.0f, h = 0.0f;
        #pragma unroll
        for (int jj = 0; jj < 16; ++jj) {
            const float pw = Pow[mrow * 64 + p16 + jj];
            g = fmaf(pw, Pf[p16 + jj], g);
            h = fmaf(pw, Qf[p16 + jj], h);
        }
        g += __shfl_xor(g, 1, 64); g += __shfl_xor(g, 2, 64);
        h += __shfl_xor(h, 1, 64); h += __shfl_xor(h, 2, 64);
        if ((tid & 3) == 0) { Gf[mrow] = g; Hf[mrow] = h; }
    }
    __syncthreads();
    // ---- setup 3: CAT/TG matrices + Hcp prefix + cq + A64 table ----
    {
        const int r0 = tid >> 2, c0 = (tid & 3) * 16;
        #pragma unroll
        for (int jj = 0; jj < 16; ++jj) {
            const int j = c0 + jj;
            CATb[r0 * 72 + j] = f2bs(Pow[(r0 + 1) * 64 + j]);
            TGb [r0 * 72 + j] = (j < r0)  ? f2bs(Gf[r0 - j])
                              : (j == r0) ? f2bs(Gf[0] + Dw)   // Dw*x folded in
                                          : (unsigned short)0;
        }
        if (tid < 64) {
            float v = Hf[tid];
            #pragma unroll
            for (int dl = 1; dl < 64; dl <<= 1) {
                const float t = __shfl(v, (tid - dl) & 63, 64);
                v += (tid >= dl) ? t : 0.0f;
            }
            HcpS[tid] = v + Db;
            const float A64 = Pow[64 * 64 + tid];
            A64S[tid] = A64;
            cqS[tid]  = Qf[tid] * (1.0f - A64) / (1.0f - Anf[tid]);
        }
    }
    __syncthreads();

    // ---- loop-invariant regs: ONLY MA' fragments (32), built from Pow ----
    s8v aMA[4][2];
    #pragma unroll
    for (int rt = 0; rt < 4; ++rt) {
        const int n = rt * 16 + m16;
        const float pn = Pf[n];
        #pragma unroll
        for (int kb = 0; kb < 2; ++kb) {
            s8v f;
            #pragma unroll
            for (int jj = 0; jj < 8; ++jj) {
                const int j = kb * 32 + q8 + jj;
                f[jj] = (short)f2bs(pn * Pow[(63 - j) * 64 + n]);
            }
            aMA[rt][kb] = f;
        }
    }
    float sig0[4][4];
    #pragma unroll
    for (int rt = 0; rt < 4; ++rt)
        #pragma unroll
        for (int r = 0; r < 4; ++r) sig0[rt][r] = 0.0f;
    __syncthreads();   // Pow reads done before scan overwrites Sigb

    // ---- prologue: pack group-0 B-frags in registers ----
    s8v bx0, bx1;
    bx0[0]=(short)f2bs(xa.x); bx0[1]=(short)f2bs(xa.y);
    bx0[2]=(short)f2bs(xa.z); bx0[3]=(short)f2bs(xa.w);
    bx0[4]=(short)f2bs(xb.x); bx0[5]=(short)f2bs(xb.y);
    bx0[6]=(short)f2bs(xb.z); bx0[7]=(short)f2bs(xb.w);
    bx1[0]=(short)f2bs(xc.x); bx1[1]=(short)f2bs(xc.y);
    bx1[2]=(short)f2bs(xc.z); bx1[3]=(short)f2bs(xc.w);
    bx1[4]=(short)f2bs(xd.x); bx1[5]=(short)f2bs(xd.y);
    bx1[6]=(short)f2bs(xd.z); bx1[7]=(short)f2bs(xd.w);

    float psum = 0.0f, pmax = -1e30f;

    #pragma unroll 1
    for (int g = 0; g < 8; ++g) {
        // issue-early loads for group g+1 (drain covered by whole body)
        float4 ya, yb, yc, yd;
        if (g < 7) {
            const float* xg = xrow + (g + 1) * 512;
            ya = ((const float4*)xg)[0];
            yb = ((const float4*)xg)[1];
            yc = ((const float4*)(xg + 32))[0];
            yd = ((const float4*)(xg + 32))[1];
        }
        // ---- B + scan fused per rt: vB consumed immediately ----
        #pragma unroll
        for (int rt = 0; rt < 4; ++rt) {
            const f4v cqv = *(const f4v*)&cqS[rt * 16 + q4];
            f4v t = __builtin_amdgcn_mfma_f32_16x16x32_bf16(aMA[rt][0], bx0, cqv, 0, 0, 0);
            const f4v vBq = __builtin_amdgcn_mfma_f32_16x16x32_bf16(aMA[rt][1], bx1, t, 0, 0, 0);
            const f4v a64q = *(const f4v*)&A64S[rt * 16 + q4];
            u4v sg;
            #pragma unroll
            for (int r = 0; r < 4; ++r) {
                const float a  = a64q[r];
                const float a2 = a * a, a4 = a2 * a2;
                const float acv = (cc1 ? a : 1.0f) * (cc2 ? a2 : 1.0f)
                                * (cc4 ? a4 : 1.0f);           // a^c, recomputed
                const float v  = vBq[r];
                const float i1 = fmaf(a,  dpp_shr2(v),  v);
                const float i2 = fmaf(a2, dpp_shr4(i1), i1);
                const float i3 = fmaf(a4, dpp_shr8(i2), i2);
                const float e  = dpp_shr2(i3);                 // i_{c-1}
                const float se = fmaf(acv, sig0[rt][r], e);
                const float S  = swz_or14(i3);                 // bcast c=7
                sig0[rt][r] = fmaf(a4 * a4, sig0[rt][r], S);   // A^512 advance
                sg[r] = f2bs(se);
            }
            *(u4v*)&Sigb[pcol * 72 + rt * 16 + q4] = sg;
        }
        const s8v bs0 = *(const s8v*)&Sigb[pcol * 72 + q8];
        const s8v bs1 = *(const s8v*)&Sigb[pcol * 72 + 32 + q8];
        // ---- D: y = Hcp + CAT x Sig + TG x Xb -> gelu -> pool ----
        #pragma unroll
        for (int rt = 0; rt < 4; ++rt) {
            const int ro = (rt * 16 + m16) * 72 + q8;
            const f4v hcpv = *(const f4v*)&HcpS[rt * 16 + q4];
            __builtin_amdgcn_s_setprio(1);
            f4v acc = __builtin_amdgcn_mfma_f32_16x16x32_bf16(
                          *(const s8v*)&CATb[ro], bs0, hcpv, 0, 0, 0);
            acc = __builtin_amdgcn_mfma_f32_16x16x32_bf16(
                          *(const s8v*)&CATb[ro + 32], bs1, acc, 0, 0, 0);
            acc = __builtin_amdgcn_mfma_f32_16x16x32_bf16(
                          *(const s8v*)&TGb[ro], bx0, acc, 0, 0, 0);
            acc = __builtin_amdgcn_mfma_f32_16x16x32_bf16(
                          *(const s8v*)&TGb[ro + 32], bx1, acc, 0, 0, 0);
            __builtin_amdgcn_s_setprio(0);
            #pragma unroll
            for (int r = 0; r < 4; ++r) {
                const float yt = acc[r];
                const float y2 = yt * yt;
                const float zn = yt * fmaf(-0.10294272f, y2, -2.30220437f);
                const float h  = yt * __builtin_amdgcn_rcpf(1.0f + exp2f(zn));
                psum += h;
                pmax = fmaxf(pmax, h);
            }
        }
        // ---- rotate prefetch into B-frags for g+1 ----
        if (g < 7) {
            bx0[0]=(short)f2bs(ya.x); bx0[1]=(short)f2bs(ya.y);
            bx0[2]=(short)f2bs(ya.z); bx0[3]=(short)f2bs(ya.w);
            bx0[4]=(short)f2bs(yb.x); bx0[5]=(short)f2bs(yb.y);
            bx0[6]=(short)f2bs(yb.z); bx0[7]=(short)f2bs(yb.w);
            bx1[0]=(short)f2bs(yc.x); bx1[1]=(short)f2bs(yc.y);
            bx1[2]=(short)f2bs(yc.z); bx1[3]=(short)f2bs(yc.w);
            bx1[4]=(short)f2bs(yd.x); bx1[5]=(short)f2bs(yd.y);
            bx1[6]=(short)f2bs(yd.z); bx1[7]=(short)f2bs(yd.w);
        }
    }

    // ---- pool: reduce across lanes sharing parity (b_loc = lane&1) ----
    #pragma unroll
    for (int dl = 2; dl <= 32; dl <<= 1) {
        psum += __shfl_xor(psum, dl, 64);
        pmax  = fmaxf(pmax, __shfl_xor(pmax, dl, 64));
    }
    // ---- fused head: out[b,c] += avg*W[d,c] + max*W[D+d,c] (+bias once) ----
    if (lane < 2) {
        const int bg = quarter * 8 + wid * 2 + lane;
        const float s  = psum * (1.0f / SEQ);
        #pragma unroll
        for (int c = 0; c < NCLS; ++c) {
            float contrib = s    * W_head[d * NCLS + c]
                          + pmax * W_head[(DMODEL + d) * NCLS + c];
            if (d == 0) contrib += b_head[c];   // each (b,c) gets bias once
            atomicAdd(&out[bg * NCLS + c], contrib);
        }
    }
}

extern "C" void kernel_launch(void* const* d_in, const int* in_sizes, int n_in,
                              void* d_out, int out_size, void* d_ws, size_t ws_size,
                              hipStream_t stream) {
    const float* x      = (const float*)d_in[0];
    const float* w_in   = (const float*)d_in[1];
    const float* b_in   = (const float*)d_in[2];
    const float* A_diag = (const float*)d_in[3];
    const float* B_in   = (const float*)d_in[4];
    const float* C_out  = (const float*)d_in[5];
    const float* D_skip = (const float*)d_in[6];
    const float* W_head = (const float*)d_in[7];
    const float* b_head = (const float*)d_in[8];
    float* out = (float*)d_out;

    hipMemsetAsync(out, 0, BATCH * NCLS * sizeof(float), stream);
    ssm_mfma_kernel<<<DMODEL * 4, 256, 0, stream>>>(x, w_in, b_in, A_diag, B_in,
                                                    C_out, D_skip, W_head, b_head, out);
}

// Round 8
// 168.579 us; speedup vs baseline: 1.6877x; 1.0138x over previous
//
#include <hip/hip_runtime.h>
#include <hip/hip_bf16.h>

#define BATCH 32
#define SEQ 4096
#define DMODEL 256
#define NCLS 5

typedef short          s8v  __attribute__((ext_vector_type(8)));  // 8 bf16 frag
typedef unsigned short u8v  __attribute__((ext_vector_type(8)));
typedef unsigned short u4v  __attribute__((ext_vector_type(4)));
typedef float          f4v  __attribute__((ext_vector_type(4)));  // C/D frag

// RNE fp32->bf16 via compiler path (fuses to v_cvt_pk_bf16_f32, m240)
__device__ __forceinline__ unsigned short f2bs(float f) {
    __hip_bfloat16 h = __float2bfloat16(f);
    return *reinterpret_cast<unsigned short*>(&h);
}
// DPP row_shr within 16-lane rows, 0-fill (bound_ctrl) -- rows align with m16
__device__ __forceinline__ float dpp_shr4(float v) {
    return __int_as_float(__builtin_amdgcn_update_dpp(
        0, __float_as_int(v), 0x114, 0xF, 0xF, true));
}
__device__ __forceinline__ float dpp_shr8(float v) {
    return __int_as_float(__builtin_amdgcn_update_dpp(
        0, __float_as_int(v), 0x118, 0xF, 0xF, true));
}
// ds_swizzle BitMode: lane -> lane|12 (broadcast chunk-3 lane of each 4-group)
__device__ __forceinline__ float swz_or12(float v) {
    return __int_as_float(__builtin_amdgcn_ds_swizzle(
        __float_as_int(v), 0x019F));
}

// R8 = the R1 43.3us kernel (empirical best; 2.5x faster than every
// restructuring attempt since) + only verified-safe deltas:
//  (1) Pow (16.6KB, setup-only) aliased onto Xb/Sigb -> LDS 82944->66048.
//      R1 was 1024 B over the 81920 2-blocks/CU threshold -- i.e. R1 was
//      LDS-limited, not register-limited. If combined regs fit 128, the
//      2nd block becomes resident (free upside; no downside).
//  (2) f2b -> __float2bfloat16 (cvt_pk path, ~-48 VALU/group of ~420).
//  (3) gelu exp2f with log2(e) folded (-16 VALU/group).
//  (4) head fused via atomicAdd (drops head launch + pooled round-trip).
// Structure unchanged from R1: one block per channel d, 8 waves; wave wid
// owns batches wid*4..+3: col m16 -> (b=wid*4+(m16&3), chunk=m16>>2);
// ZERO __syncthreads in the 16-group loop (all LDS traffic wave-private,
// in-order DS pipe). Per group (256 timesteps):
//   B: vB[n,col] = MA'[n,j]*Xb[j,col] + cq   (MA'[n][j]=Pn*A^{63-j}, C-in=cq)
//   scan: 4-chunk prefix in-wave via DPP row_shr4/8 + or12 broadcast;
//      sigma0' = A^256*sigma0 + bcast(incl@c=3); Sig snapshot = e + a^c*sigma0
//   D: y = CAT x Sig + TG x Xb (C-in = Hcp; Dw*x folded into TG diagonal)
//      -> gelu -> per-lane pool; fused atomic head at the end.
// MFMA 16x16x32 bf16 layouts (verified m89/m91): A[m=lane&15][k=quad*8+j],
// B[k=quad*8+j][n=lane&15], D: col=lane&15, row=quad*4+reg.
__global__ __launch_bounds__(512) void ssm_mfma_kernel(
    const float* __restrict__ x,      // [B, T]
    const float* __restrict__ w_in,   // [D]
    const float* __restrict__ b_in,   // [D]
    const float* __restrict__ A_diag, // [D, 64]
    const float* __restrict__ B_in,   // [D, 64]
    const float* __restrict__ C_out,  // [D, 64]
    const float* __restrict__ D_skip, // [D]
    const float* __restrict__ W_head, // [2D, NCLS]
    const float* __restrict__ b_head, // [NCLS]
    float* __restrict__ out)          // [B, NCLS] (pre-zeroed, atomic accum)
{
    // Xb | Sigb carved from one buffer; Pow[65*64] f32 (16640 B, setup-only)
    // aliases the same storage (36864 B) -- saves 16.6 KB vs R1.
    __shared__ __align__(16) unsigned char XSbuf[2 * 128 * 72 * 2];
    __shared__ unsigned short MAb [64 * 72];
    __shared__ unsigned short CATb[64 * 72];
    __shared__ unsigned short TGb [64 * 72];
    __shared__ float Pf[64], Qf[64], Gf[64], Hf[64], HcpS[64], Anf[64];

    unsigned short* Xb   = (unsigned short*)XSbuf;             // [128*72]
    unsigned short* Sigb = (unsigned short*)(XSbuf + 128 * 72 * 2);
    float*          Pow  = (float*)XSbuf;                      // [65*64] setup

    const int tid  = threadIdx.x;
    const int lane = tid & 63;
    const int wid  = tid >> 6;
    const int m16  = lane & 15;
    const int q    = lane >> 4;
    const int q4   = q * 4;
    const int q8   = q * 8;
    const int d    = blockIdx.x;

    const float wd = w_in[d], bd = b_in[d];
    const float Dw = D_skip[d] * wd;
    const float Db = D_skip[d] * bd;

    // lane's (batch, chunk-in-group) and private LDS column
    const int bcol = wid * 4 + (m16 & 3);
    const int cch  = m16 >> 2;
    const int pcol = wid * 16 + m16;
    const float* xrow = x + bcol * SEQ + cch * 64 + q * 16;
    unsigned short* xdst = &Xb[pcol * 72 + q * 16];

    // issue group-0 stage loads immediately; setup hides the latency
    float4 xl0 = ((const float4*)xrow)[0];
    float4 xl1 = ((const float4*)xrow)[1];
    float4 xl2 = ((const float4*)xrow)[2];
    float4 xl3 = ((const float4*)xrow)[3];

    // ---- setup 1: per-n tables + power table (wave 0) ----
    if (tid < 64) {
        const int n = tid;
        const float An = A_diag[d * 64 + n];
        const float CB = B_in[d * 64 + n] * C_out[d * 64 + n];
        Anf[n] = An; Pf[n] = CB * wd; Qf[n] = CB * bd;
        float p = 1.0f;
        for (int m = 0; m <= 64; ++m) { Pow[m * 64 + n] = p; p *= An; }
    }
    __syncthreads();
    // ---- setup 2: G/H = Pow x {P,Q} matvec, 8 threads per row ----
    {
        const int mrow = tid >> 3, p8 = (tid & 7) * 8;
        float g = 0.0f, h = 0.0f;
        #pragma unroll
        for (int jj = 0; jj < 8; ++jj) {
            const float pw = Pow[mrow * 64 + p8 + jj];
            g = fmaf(pw, Pf[p8 + jj], g);
            h = fmaf(pw, Qf[p8 + jj], h);
        }
        g += __shfl_xor(g, 1, 64); g += __shfl_xor(g, 2, 64); g += __shfl_xor(g, 4, 64);
        h += __shfl_xor(h, 1, 64); h += __shfl_xor(h, 2, 64); h += __shfl_xor(h, 4, 64);
        if ((tid & 7) == 0) { Gf[mrow] = g; Hf[mrow] = h; }
    }
    __syncthreads();
    // ---- setup 3: MA'/CAT/TG matrices + Hcp prefix (shfl scan) ----
    {
        const int r0 = tid >> 3, c0 = (tid & 7) * 8;
        #pragma unroll
        for (int jj = 0; jj < 8; ++jj) {
            const int j = c0 + jj;
            MAb [r0 * 72 + j] = f2bs(Pf[r0] * Pow[(63 - j) * 64 + r0]);
            CATb[r0 * 72 + j] = f2bs(Pow[(r0 + 1) * 64 + j]);
            TGb [r0 * 72 + j] = (j < r0)  ? f2bs(Gf[r0 - j])
                              : (j == r0) ? f2bs(Gf[0] + Dw)   // Dw*x folded in
                                          : (unsigned short)0;
        }
        if (tid < 64) {
            float v = Hf[tid];
            #pragma unroll
            for (int dl = 1; dl < 64; dl <<= 1) {
                const float t = __shfl(v, (tid - dl) & 63, 64);
                v += (tid >= dl) ? t : 0.0f;
            }
            HcpS[tid] = v + Db;
        }
    }
    __syncthreads();

    // ---- loop-invariant registers (frags park in unified AGPR file) ----
    s8v aMA[4][2], aCAT[4][2], aTG[4][2];
    #pragma unroll
    for (int rt = 0; rt < 4; ++rt)
        #pragma unroll
        for (int kb = 0; kb < 2; ++kb) {
            const int off = (rt * 16 + m16) * 72 + kb * 32 + q8;
            aMA [rt][kb] = *(const s8v*)&MAb [off];
            aCAT[rt][kb] = *(const s8v*)&CATb[off];
            aTG [rt][kb] = *(const s8v*)&TGb [off];
        }
    f4v cq[4], hcp[4];
    float a64v[4][4], sig0[4][4];
    #pragma unroll
    for (int rt = 0; rt < 4; ++rt)
        #pragma unroll
        for (int r = 0; r < 4; ++r) {
            const int nn = rt * 16 + q4 + r;
            const float A64 = Pow[64 * 64 + nn];
            a64v[rt][r] = A64;
            cq[rt][r]   = Qf[nn] * (1.0f - A64) / (1.0f - Anf[nn]);
            hcp[rt][r]  = HcpS[nn];
            sig0[rt][r] = 0.0f;
        }
    const bool cc1 = (cch & 1) != 0;
    const bool cc2 = (cch & 2) != 0;
    __syncthreads();   // all Pow reads done before Xb staging overwrites it

    // ---- prologue: stage group 0 (wave-private cols) ----
    {
        u8v lo, hi;
        lo[0]=f2bs(xl0.x); lo[1]=f2bs(xl0.y); lo[2]=f2bs(xl0.z); lo[3]=f2bs(xl0.w);
        lo[4]=f2bs(xl1.x); lo[5]=f2bs(xl1.y); lo[6]=f2bs(xl1.z); lo[7]=f2bs(xl1.w);
        hi[0]=f2bs(xl2.x); hi[1]=f2bs(xl2.y); hi[2]=f2bs(xl2.z); hi[3]=f2bs(xl2.w);
        hi[4]=f2bs(xl3.x); hi[5]=f2bs(xl3.y); hi[6]=f2bs(xl3.z); hi[7]=f2bs(xl3.w);
        *(u8v*)(xdst)     = lo;
        *(u8v*)(xdst + 8) = hi;
    }

    float psum = 0.0f, pmax = -1e30f;

    #pragma unroll 1
    for (int g = 0; g < 16; ++g) {
        // issue-early loads for group g+1 (complete under this body)
        float4 yl0, yl1, yl2, yl3;
        if (g < 15) {
            const float4* xg = (const float4*)(xrow + (g + 1) * 256);
            yl0 = xg[0]; yl1 = xg[1]; yl2 = xg[2]; yl3 = xg[3];
        }
        // ---- B: v = cq + MA' x Xb ----
        const s8v bx0 = *(const s8v*)&Xb[pcol * 72 + q8];
        const s8v bx1 = *(const s8v*)&Xb[pcol * 72 + 32 + q8];
        f4v vB[4];
        #pragma unroll
        for (int rt = 0; rt < 4; ++rt) {
            vB[rt] = __builtin_amdgcn_mfma_f32_16x16x32_bf16(aMA[rt][0], bx0, cq[rt], 0, 0, 0);
            vB[rt] = __builtin_amdgcn_mfma_f32_16x16x32_bf16(aMA[rt][1], bx1, vB[rt], 0, 0, 0);
        }
        // stage write for g+1 (bx already consumed into regs; same-wave cols)
        if (g < 15) {
            u8v lo, hi;
            lo[0]=f2bs(yl0.x); lo[1]=f2bs(yl0.y); lo[2]=f2bs(yl0.z); lo[3]=f2bs(yl0.w);
            lo[4]=f2bs(yl1.x); lo[5]=f2bs(yl1.y); lo[6]=f2bs(yl1.z); lo[7]=f2bs(yl1.w);
            hi[0]=f2bs(yl2.x); hi[1]=f2bs(yl2.y); hi[2]=f2bs(yl2.z); hi[3]=f2bs(yl2.w);
            hi[4]=f2bs(yl3.x); hi[5]=f2bs(yl3.y); hi[6]=f2bs(yl3.z); hi[7]=f2bs(yl3.w);
            *(u8v*)(xdst)     = lo;
            *(u8v*)(xdst + 8) = hi;
        }
        // ---- in-wave 4-chunk scan (DPP) + Sig snapshot ----
        #pragma unroll
        for (int rt = 0; rt < 4; ++rt) {
            u4v sg;
            #pragma unroll
            for (int r = 0; r < 4; ++r) {
                const float a  = a64v[rt][r];
                const float v  = vB[rt][r];
                const float t1 = dpp_shr4(v);            // v@(c-1), 0 at c=0
                const float i1 = fmaf(a, t1, v);
                const float t2 = dpp_shr8(i1);           // 0 at c<2
                const float e  = fmaf(a, t2, t1);        // exact exclusive prefix
                const float ac = (cc1 ? a : 1.0f) * (cc2 ? a * a : 1.0f);  // a^c
                const float se = fmaf(ac, sig0[rt][r], e);   // entering state
                const float i2 = fmaf(a, e, v);          // inclusive prefix
                const float S  = swz_or12(i2);           // broadcast c=3 lane
                const float a2 = a * a;
                sig0[rt][r] = fmaf(a2 * a2, sig0[rt][r], S);   // A^256 advance
                sg[r] = f2bs(se);
            }
            *(u4v*)&Sigb[pcol * 72 + rt * 16 + q4] = sg;
        }
        // ---- D: y = Hcp + CAT x Sig + TG x Xb -> gelu -> pool ----
        const s8v bs0 = *(const s8v*)&Sigb[pcol * 72 + q8];
        const s8v bs1 = *(const s8v*)&Sigb[pcol * 72 + 32 + q8];
        #pragma unroll
        for (int rt = 0; rt < 4; ++rt) {
            f4v acc = __builtin_amdgcn_mfma_f32_16x16x32_bf16(aCAT[rt][0], bs0, hcp[rt], 0, 0, 0);
            acc = __builtin_amdgcn_mfma_f32_16x16x32_bf16(aCAT[rt][1], bs1, acc, 0, 0, 0);
            acc = __builtin_amdgcn_mfma_f32_16x16x32_bf16(aTG [rt][0], bx0, acc, 0, 0, 0);
            acc = __builtin_amdgcn_mfma_f32_16x16x32_bf16(aTG [rt][1], bx1, acc, 0, 0, 0);
            #pragma unroll
            for (int r = 0; r < 4; ++r) {
                const float yt = acc[r];
                const float y2 = yt * yt;
                // gelu tanh-approx, log2(e) folded into the polynomial
                const float zn = yt * fmaf(-0.10294272f, y2, -2.30220437f);
                const float h  = yt * __builtin_amdgcn_rcpf(1.0f + exp2f(zn));
                psum += h;
                pmax = fmaxf(pmax, h);
            }
        }
    }

    // ---- pool: reduce lanes sharing b_loc = lane&3 (xor chunk+q bits) ----
    #pragma unroll
    for (int dl = 4; dl <= 32; dl <<= 1) {
        psum += __shfl_xor(psum, dl, 64);
        pmax  = fmaxf(pmax, __shfl_xor(pmax, dl, 64));
    }
    // ---- fused head: out[b,c] += avg*W[d,c] + max*W[D+d,c] (+bias once) ----
    if (lane < 4) {
        const int b = wid * 4 + lane;
        const float s = psum * (1.0f / SEQ);
        #pragma unroll
        for (int c = 0; c < NCLS; ++c) {
            float contrib = s    * W_head[d * NCLS + c]
                          + pmax * W_head[(DMODEL + d) * NCLS + c];
            if (d == 0) contrib += b_head[c];   // each (b,c) gets bias once
            atomicAdd(&out[b * NCLS + c], contrib);
        }
    }
}

extern "C" void kernel_launch(void* const* d_in, const int* in_sizes, int n_in,
                              void* d_out, int out_size, void* d_ws, size_t ws_size,
                              hipStream_t stream) {
    const float* x      = (const float*)d_in[0];
    const float* w_in   = (const float*)d_in[1];
    const float* b_in   = (const float*)d_in[2];
    const float* A_diag = (const float*)d_in[3];
    const float* B_in   = (const float*)d_in[4];
    const float* C_out  = (const float*)d_in[5];
    const float* D_skip = (const float*)d_in[6];
    const float* W_head = (const float*)d_in[7];
    const float* b_head = (const float*)d_in[8];
    float* out = (float*)d_out;

    hipMemsetAsync(out, 0, BATCH * NCLS * sizeof(float), stream);
    ssm_mfma_kernel<<<DMODEL, 512, 0, stream>>>(x, w_in, b_in, A_diag, B_in,
                                                C_out, D_skip, W_head, b_head, out);
}